// Round 7
// baseline (1224.761 us; speedup 1.0000x reference)
//
#include <hip/hip_runtime.h>
#include <hip/hip_bf16.h>

#define NN 100000
#define EE 1600000
#define BB 256
#define F_NODE 35
#define F_EDGE 10
#define HH 64
#define IN_DIM 138
#define N_CONV 3
#define EPSBN 1e-5f
#define NB1 ((NN + 255) / 256)  // 391 scan blocks

// conv tiling: 5000 blocks x 2 waves; block covers 320 edges (waves split cols)
#define NBLK 5000
#define NGROUPS 20          // even (loop unrolled by 2)
#define SUBLEN 80           // 4*NGROUPS
#define EPB 320             // 16*NGROUPS edges per block
#define EFSTR 12            // padded ef row in halves (24 B)

#define LOG2E 1.442695041f
#define LN2   0.6931471806f

typedef _Float16 half8 __attribute__((ext_vector_type(8)));
typedef float floatx4 __attribute__((ext_vector_type(4)));

// softplus in log2 domain: ln2 * log2(1 + 2^(x*log2e)) — exact for all ranges
__device__ __forceinline__ float softplus_fast(float x) {
    float t = __builtin_amdgcn_exp2f(LOG2E * x);
    return LN2 * __builtin_amdgcn_logf(1.0f + t);
}
// sigmoid(g)*softplus(c), 10 VALU instrs (4 quarter-rate)
__device__ __forceinline__ float mpair(float g, float c) {
    float tg = __builtin_amdgcn_exp2f(-LOG2E * g);
    float sig = __builtin_amdgcn_rcpf(1.0f + tg);
    float tc = __builtin_amdgcn_exp2f(LOG2E * c);
    float sp = LN2 * __builtin_amdgcn_logf(1.0f + tc);
    return sig * sp;
}

// ---------------- sort by src: hist+rank, scan, perm(+scan3), gather ----------------
__global__ __launch_bounds__(256)
void hist_rank_kernel(const int* __restrict__ src, int* __restrict__ cnt,
                      int* __restrict__ rank) {
    int e = blockIdx.x * 256 + threadIdx.x;
    rank[e] = atomicAdd(&cnt[src[e]], 1);
}

__global__ __launch_bounds__(256)
void scan1_kernel(int* __restrict__ cnt, int* __restrict__ bsum, int n) {
    __shared__ int ls[256];
    int t = threadIdx.x;
    int i = blockIdx.x * 256 + t;
    int v = (i < n) ? cnt[i] : 0;
    ls[t] = v;
    __syncthreads();
#pragma unroll
    for (int off = 1; off < 256; off <<= 1) {
        int add = (t >= off) ? ls[t - off] : 0;
        __syncthreads();
        ls[t] += add;
        __syncthreads();
    }
    if (i < n) cnt[i] = ls[t] - v;
    if (t == 255) bsum[blockIdx.x] = ls[255];
}

__global__ __launch_bounds__(512)
void scan2_kernel(int* __restrict__ bsum, int nb) {
    __shared__ int ls[512];
    int t = threadIdx.x;
    int v = (t < nb) ? bsum[t] : 0;
    ls[t] = v;
    __syncthreads();
#pragma unroll
    for (int off = 1; off < 512; off <<= 1) {
        int add = (t >= off) ? ls[t - off] : 0;
        __syncthreads();
        ls[t] += add;
        __syncthreads();
    }
    if (t < nb) bsum[t] = ls[t] - v;
}

__global__ __launch_bounds__(256)
void perm_kernel(const int* __restrict__ src, const int* __restrict__ rank,
                 const int* __restrict__ offs, const int* __restrict__ bsum,
                 int* __restrict__ perm) {
    int e = blockIdx.x * 256 + threadIdx.x;
    int s = src[e];
    perm[offs[s] + bsum[s >> 8] + rank[e]] = e;
}

__global__ __launch_bounds__(256)
void gather_kernel(const int* __restrict__ perm,
                   const int* __restrict__ src, const int* __restrict__ dst,
                   const float* __restrict__ ef,
                   int* __restrict__ ssorted, int* __restrict__ dsorted,
                   _Float16* __restrict__ ef16) {
    int pos = blockIdx.x * 256 + threadIdx.x;
    int e = perm[pos];
    ssorted[pos] = src[e];
    dsorted[pos] = dst[e];
    const float2* efe = (const float2*)(ef + (size_t)e * F_EDGE);
    uint* op = (uint*)(ef16 + (size_t)pos * EFSTR);
#pragma unroll
    for (int i = 0; i < 5; i++) {
        float2 v = efe[i];
        _Float16 h0 = (_Float16)v.x;
        _Float16 h1 = (_Float16)v.y;
        op[i] = (uint)*(unsigned short*)&h0 | ((uint)*(unsigned short*)&h1 << 16);
    }
    op[5] = 0u;
}

// weights -> f16 transposed [layer][n=0..127][k=0..159], zero-padded K
__global__ __launch_bounds__(256)
void prep_w_kernel(const float* __restrict__ gw, const float* __restrict__ cw,
                   _Float16* __restrict__ wT) {
    int idx = blockIdx.x * 256 + threadIdx.x;
    if (idx >= 3 * 128 * 160) return;
    int k = idx % 160;
    int n = (idx / 160) & 127;
    int layer = idx / (160 * 128);
    float v = 0.f;
    if (k < IN_DIM)
        v = (n < 64) ? gw[layer * IN_DIM * HH + k * HH + n]
                     : cw[layer * IN_DIM * HH + k * HH + (n - 64)];
    wT[idx] = (_Float16)v;
}

// ---------------- embed (writes h16 only) ----------------
__global__ __launch_bounds__(256)
void embed_kernel(const float* __restrict__ nf, const float* __restrict__ w,
                  const float* __restrict__ bias, _Float16* __restrict__ h16, int n) {
    __shared__ float wl[F_NODE * HH];
    int tid = threadIdx.x;
    for (int i = tid; i < F_NODE * HH; i += 256) wl[i] = w[i];
    __syncthreads();
    int idx = blockIdx.x * 256 + tid;
    int node = idx >> 6, j = idx & 63;
    if (node >= n) return;
    float acc = bias[j];
    const float* row = nf + node * F_NODE;
#pragma unroll
    for (int k = 0; k < F_NODE; k++) acc += row[k] * wl[k * HH + j];
    h16[idx] = (_Float16)acc;
}

// ---------------- conv: barrier-free, LDS-free, col-split, 2-deep prefetch ----------------
__device__ __forceinline__ void loadA(uint4* A,
                                      const _Float16* __restrict__ h16,
                                      const _Float16* __restrict__ ef16,
                                      int s, int d, int eg, int quad) {
    const uint4* hs = (const uint4*)(h16 + (size_t)s * HH);
    const uint4* hd = (const uint4*)(h16 + (size_t)d * HH);
    A[0] = hs[quad];
    A[1] = hs[quad + 4];
    A[2] = hd[quad];
    A[3] = hd[quad + 4];
    uint4 z; z.x = z.y = z.z = z.w = 0u;
    A[4] = z;
    const _Float16* p = ef16 + (size_t)eg * EFSTR;
    if (quad == 0) {
        uint2 a = *(const uint2*)p;
        uint2 b = *(const uint2*)(p + 4);
        A[4].x = a.x; A[4].y = a.y; A[4].z = b.x; A[4].w = b.y;
    } else if (quad == 1) {
        uint2 a = *(const uint2*)(p + 8);
        A[4].x = a.x; A[4].y = a.y;
    }
}

__global__ __launch_bounds__(128, 3)
void edge_conv_mfma(const _Float16* __restrict__ h16,
                    const int* __restrict__ esrc,
                    const int* __restrict__ edst,
                    const _Float16* __restrict__ ef16,
                    const _Float16* __restrict__ wT,
                    const float* __restrict__ gb, const float* __restrict__ cb,
                    float* __restrict__ agg) {
    int lane = threadIdx.x & 63;
    int w = threadIdx.x >> 6;          // wave 0/1: col-split
    int quad = lane >> 4, n15 = lane & 15;
    int base = blockIdx.x * EPB + ((n15 >> 2) * SUBLEN) + (n15 & 3);

    // this wave's 4 B-tiles: gate {2w,2w+1}, cand {4+2w,4+2w+1} -> 80 VGPRs
    int tg = 2 * w;
    half8 B[4][5];
#pragma unroll
    for (int j = 0; j < 2; j++) {
        const _Float16* wrg = wT + ((tg + j) * 16 + n15) * 160 + quad * 8;
        const _Float16* wrc = wT + ((4 + tg + j) * 16 + n15) * 160 + quad * 8;
#pragma unroll
        for (int ks = 0; ks < 5; ks++) {
            B[j][ks]     = *(const half8*)(wrg + ks * 32);
            B[2 + j][ks] = *(const half8*)(wrc + ks * 32);
        }
    }
    float gb0 = gb[tg * 16 + n15], gb1 = gb[(tg + 1) * 16 + n15];
    float cb0 = cb[tg * 16 + n15], cb1 = cb[(tg + 1) * 16 + n15];
    int colbase = tg * 16 + n15;

    int sprev = -1;
    float am0 = 0.f, am1 = 0.f;

    // pipeline state: A[k] holds group g+k; (sp,dp)[k] are indices for group g+2+k
    uint4 A[2][5];
    int sg2[2], sp[2], dp[2];
    {
        int e0 = base, e1 = base + 4;
        int s0 = esrc[e0], d0 = edst[e0];
        int s1 = esrc[e1], d1 = edst[e1];
        loadA(A[0], h16, ef16, s0, d0, e0, quad);
        loadA(A[1], h16, ef16, s1, d1, e1, quad);
        sg2[0] = s0; sg2[1] = s1;
        int e2 = base + 8, e3 = base + 12;
        sp[0] = esrc[e2]; dp[0] = edst[e2];
        sp[1] = esrc[e3]; dp[1] = edst[e3];
    }

    for (int g = 0; g < NGROUPS; g += 2) {
#pragma unroll
        for (int k = 0; k < 2; k++) {
            int gk = g + k;
            int s_cur = sg2[k];

            // accumulators init with bias (bias add folded into MFMA chain)
            floatx4 acc[4];
            acc[0] = (floatx4){gb0, gb0, gb0, gb0};
            acc[1] = (floatx4){gb1, gb1, gb1, gb1};
            acc[2] = (floatx4){cb0, cb0, cb0, cb0};
            acc[3] = (floatx4){cb1, cb1, cb1, cb1};

#pragma unroll
            for (int ks = 0; ks < 5; ks++) {
                half8 a = __builtin_bit_cast(half8, A[k][ks]);
#pragma unroll
                for (int t = 0; t < 4; t++)
                    acc[t] = __builtin_amdgcn_mfma_f32_16x16x32_f16(a, B[t][ks], acc[t], 0, 0, 0);
            }

            // refill A[k] for group gk+2 (indices prefetched 2 bodies ago)
            int gl = (gk + 2 < NGROUPS) ? gk + 2 : NGROUPS - 1;
            loadA(A[k], h16, ef16, sp[k], dp[k], base + gl * 4, quad);
            sg2[k] = sp[k];
            int gp = (gk + 4 < NGROUPS) ? gk + 4 : NGROUPS - 1;
            int ep = base + gp * 4;
            sp[k] = esrc[ep]; dp[k] = edst[ep];

            // epilogue: activation + run-merged scatter
#pragma unroll
            for (int r = 0; r < 4; r++) {
                int sr = __shfl(s_cur, quad * 4 + r, 64);
                if (sr != sprev) {
                    if (sprev >= 0) {
                        float* p = agg + (size_t)sprev * HH + colbase;
                        atomicAdd(p, am0);
                        atomicAdd(p + 16, am1);
                    }
                    sprev = sr;
                    am0 = am1 = 0.f;
                }
                am0 += mpair(acc[0][r], acc[2][r]);
                am1 += mpair(acc[1][r], acc[3][r]);
            }
        }
    }
    if (sprev >= 0) {
        float* p = agg + (size_t)sprev * HH + colbase;
        atomicAdd(p, am0);
        atomicAdd(p + 16, am1);
    }
}

// ---------------- BN ----------------
__global__ __launch_bounds__(256)
void bn_stats_kernel(const float* __restrict__ agg, float* __restrict__ stats, int total) {
    __shared__ float ls[256], lss[256];
    int tid = threadIdx.x;
    float s = 0.f, ss = 0.f;
    for (int idx = blockIdx.x * 256 + tid; idx < total; idx += gridDim.x * 256) {
        float v = agg[idx];
        s += v;
        ss += v * v;
    }
    ls[tid] = s;
    lss[tid] = ss;
    __syncthreads();
    if (tid < 64) {
        s = ls[tid] + ls[tid + 64] + ls[tid + 128] + ls[tid + 192];
        ss = lss[tid] + lss[tid + 64] + lss[tid + 128] + lss[tid + 192];
        atomicAdd(&stats[tid], s);
        atomicAdd(&stats[64 + tid], ss);
    }
}

// h16 = softplus(h16 + BN(agg)); zeroes agg for next layer
__global__ __launch_bounds__(256)
void bn_update_kernel(_Float16* __restrict__ h16,
                      float* __restrict__ agg,
                      const float* __restrict__ stats,
                      const float* __restrict__ g, const float* __restrict__ b,
                      int total, float invN) {
    int idx = blockIdx.x * 256 + threadIdx.x;
    if (idx >= total) return;
    int j = idx & 63;
    float mu = stats[j] * invN;
    float var = stats[64 + j] * invN - mu * mu;
    var = fmaxf(var, 0.0f);
    float scale = g[j] * rsqrtf(var + EPSBN);
    float a = agg[idx];
    agg[idx] = 0.f;
    float v = (float)h16[idx] + (a - mu) * scale + b[j];
    h16[idx] = (_Float16)softplus_fast(v);
}

// ---------------- pool (reads h16) ----------------
__global__ __launch_bounds__(256)
void pool_kernel(const _Float16* __restrict__ h16, const int* __restrict__ gi,
                 float* __restrict__ pool, float* __restrict__ counts, int n) {
    int tid = threadIdx.x;
    int grp = tid >> 6;
    int j = tid & 63;
    int n0 = blockIdx.x * 64 + grp * 16;
    if (n0 >= n) return;
    int nend = n0 + 16; if (nend > n) nend = n;
    int gprev = gi[n0];
    float a = 0.f;
    int cnt = 0;
    for (int nn = n0; nn < nend; nn++) {
        int gg = gi[nn];
        if (gg != gprev) {
            atomicAdd(&pool[gprev * 64 + j], a);
            if (j == 0) atomicAdd(&counts[gprev], (float)cnt);
            a = 0.f; cnt = 0; gprev = gg;
        }
        a += (float)h16[(size_t)nn * 64 + j];
        cnt++;
    }
    atomicAdd(&pool[gprev * 64 + j], a);
    if (j == 0) atomicAdd(&counts[gprev], (float)cnt);
}

__global__ __launch_bounds__(128)
void mlp_kernel(const float* __restrict__ pool, const float* __restrict__ counts,
                const float* __restrict__ w1, const float* __restrict__ b1,
                const float* __restrict__ w2, const float* __restrict__ b2,
                const float* __restrict__ w3, const float* __restrict__ b3,
                float* __restrict__ out) {
    __shared__ float x0[64], x1[128], x2[64];
    int b = blockIdx.x, t = threadIdx.x;
    if (t < 64) {
        float c = counts[b];
        c = c < 1.f ? 1.f : c;
        x0[t] = pool[b * 64 + t] / c;
    }
    __syncthreads();
    {
        float acc = 0.f;
#pragma unroll
        for (int k = 0; k < 64; k++) acc += x0[k] * w1[k * 128 + t];
        x1[t] = softplus_fast(acc + b1[t]);
    }
    __syncthreads();
    if (t < 64) {
        float acc = 0.f;
#pragma unroll
        for (int k = 0; k < 128; k++) acc += x1[k] * w2[k * 64 + t];
        x2[t] = softplus_fast(acc + b2[t]);
    }
    __syncthreads();
    if (t == 0) {
        float acc = 0.f;
        for (int k = 0; k < 64; k++) acc += x2[k] * w3[k];
        out[b] = acc + b3[0];
    }
}

extern "C" void kernel_launch(void* const* d_in, const int* in_sizes, int n_in,
                              void* d_out, int out_size, void* d_ws, size_t ws_size,
                              hipStream_t stream) {
    const float* nf      = (const float*)d_in[0];
    const int*   ei      = (const int*)d_in[1];
    const float* ef      = (const float*)d_in[2];
    const int*   gi      = (const int*)d_in[3];
    const float* embed_w = (const float*)d_in[4];
    const float* embed_b = (const float*)d_in[5];
    const float* gate_w  = (const float*)d_in[6];
    const float* gate_b  = (const float*)d_in[7];
    const float* cand_w  = (const float*)d_in[8];
    const float* cand_b  = (const float*)d_in[9];
    const float* bn_g    = (const float*)d_in[10];
    const float* bn_b    = (const float*)d_in[11];
    const float* w1      = (const float*)d_in[12];
    const float* b1      = (const float*)d_in[13];
    const float* w2      = (const float*)d_in[14];
    const float* b2      = (const float*)d_in[15];
    const float* w3      = (const float*)d_in[16];
    const float* b3      = (const float*)d_in[17];
    float* out = (float*)d_out;

    const int NH = NN * HH;  // 6.4M
    char* p = (char*)d_ws;
    // --- zero-initialized block (single memset) ---
    int*       offs    = (int*)p;              p += (size_t)NN * 4;
    float*     agg     = (float*)p;            p += (size_t)NH * 4;
    float*     stats   = (float*)p;            p += 3 * 128 * 4;
    float*     pool    = (float*)p;            p += (size_t)BB * HH * 4;
    float*     counts  = (float*)p;            p += (size_t)BB * 4;
    size_t zero_bytes = (size_t)(p - (char*)d_ws);
    // --- rest ---
    _Float16*  h16     = (_Float16*)p;         p += (size_t)NH * 2;
    int*       ssorted = (int*)p;              p += (size_t)EE * 4;
    int*       dsorted = (int*)p;              p += (size_t)EE * 4;
    _Float16*  ef16    = (_Float16*)p;         p += (size_t)EE * EFSTR * 2;
    int*       perm    = (int*)p;              p += (size_t)EE * 4;
    int*       rank    = (int*)p;              p += (size_t)EE * 4;
    _Float16*  wTall   = (_Float16*)p;         p += (size_t)3 * 128 * 160 * 2;
    int*       bsum    = (int*)p;              p += 512 * 4;

    const int* src = ei;
    const int* dst = ei + EE;

    hipMemsetAsync(d_ws, 0, zero_bytes, stream);

    // ---- sort edges by src + weight prep ----
    hist_rank_kernel<<<EE / 256, 256, 0, stream>>>(src, offs, rank);
    prep_w_kernel<<<(3 * 128 * 160 + 255) / 256, 256, 0, stream>>>(gate_w, cand_w, wTall);
    scan1_kernel<<<NB1, 256, 0, stream>>>(offs, bsum, NN);
    scan2_kernel<<<1, 512, 0, stream>>>(bsum, NB1);
    perm_kernel<<<EE / 256, 256, 0, stream>>>(src, rank, offs, bsum, perm);
    gather_kernel<<<EE / 256, 256, 0, stream>>>(perm, src, dst, ef, ssorted, dsorted, ef16);

    // ---- embed ----
    embed_kernel<<<NH / 256, 256, 0, stream>>>(nf, embed_w, embed_b, h16, NN);

    // ---- conv layers ----
    for (int i = 0; i < N_CONV; i++) {
        edge_conv_mfma<<<NBLK, 128, 0, stream>>>(
            h16, ssorted, dsorted, ef16,
            wTall + (size_t)i * 128 * 160,
            gate_b + i * HH, cand_b + i * HH, agg);
        bn_stats_kernel<<<512, 256, 0, stream>>>(agg, stats + i * 128, NH);
        bn_update_kernel<<<NH / 256, 256, 0, stream>>>(
            h16, agg, stats + i * 128, bn_g + i * HH, bn_b + i * HH, NH, 1.0f / (float)NN);
    }

    // ---- pool + MLP ----
    pool_kernel<<<(NN + 63) / 64, 256, 0, stream>>>(h16, gi, pool, counts, NN);
    mlp_kernel<<<BB, 128, 0, stream>>>(pool, counts, w1, b1, w2, b2, w3, b3, out);
}

// Round 8
// 833.682 us; speedup vs baseline: 1.4691x; 1.4691x over previous
//
#include <hip/hip_runtime.h>
#include <hip/hip_bf16.h>

#define NN 100000
#define EE 1600000
#define BB 256
#define F_NODE 35
#define F_EDGE 10
#define HH 64
#define IN_DIM 138
#define N_CONV 3
#define EPSBN 1e-5f
#define NB1 ((NN + 255) / 256)  // 391 scan blocks

// conv tiling: 4000 blocks x 2 waves; block covers 400 edges (waves split cols)
#define NBLK 4000
#define NGROUPS 25
#define SUBLEN 100          // 4*NGROUPS
#define EPB 400             // 16*NGROUPS edges per block
#define EFSTR 12            // padded ef row in halves (24 B)

#define LOG2E 1.442695041f
#define LN2   0.6931471806f

typedef _Float16 half8 __attribute__((ext_vector_type(8)));
typedef float floatx4 __attribute__((ext_vector_type(4)));

__device__ __forceinline__ float softplus_fast(float x) {
    // ln2 * log2(1 + exp2(x*log2e)), guarded against overflow
    float t = __builtin_amdgcn_exp2f(fminf(LOG2E * x, 126.0f));
    return LN2 * __builtin_amdgcn_logf(1.0f + t);
}
// inputs pre-scaled: g2 = -log2e*g, c2 = log2e*c  ->  sigmoid(g)*log2(1+2^c2)
// (caller multiplies by LN2 via fma at accumulate time)
__device__ __forceinline__ float mpair_pre(float g2, float c2) {
    float tg = __builtin_amdgcn_exp2f(g2);            // inf ok: rcp(inf)=0
    float sig = __builtin_amdgcn_rcpf(1.0f + tg);
    float tc = __builtin_amdgcn_exp2f(fminf(c2, 126.0f));
    float l = __builtin_amdgcn_logf(1.0f + tc);       // log2
    return sig * l;
}

// ---------------- sort by src: hist+rank, scan, perm(+scan3), gather ----------------
__global__ __launch_bounds__(256)
void hist_rank_kernel(const int* __restrict__ src, int* __restrict__ cnt,
                      int* __restrict__ rank) {
    int e = blockIdx.x * 256 + threadIdx.x;
    rank[e] = atomicAdd(&cnt[src[e]], 1);
}

__global__ __launch_bounds__(256)
void scan1_kernel(int* __restrict__ cnt, int* __restrict__ bsum, int n) {
    __shared__ int ls[256];
    int t = threadIdx.x;
    int i = blockIdx.x * 256 + t;
    int v = (i < n) ? cnt[i] : 0;
    ls[t] = v;
    __syncthreads();
#pragma unroll
    for (int off = 1; off < 256; off <<= 1) {
        int add = (t >= off) ? ls[t - off] : 0;
        __syncthreads();
        ls[t] += add;
        __syncthreads();
    }
    if (i < n) cnt[i] = ls[t] - v;
    if (t == 255) bsum[blockIdx.x] = ls[255];
}

__global__ __launch_bounds__(512)
void scan2_kernel(int* __restrict__ bsum, int nb) {
    __shared__ int ls[512];
    int t = threadIdx.x;
    int v = (t < nb) ? bsum[t] : 0;
    ls[t] = v;
    __syncthreads();
#pragma unroll
    for (int off = 1; off < 512; off <<= 1) {
        int add = (t >= off) ? ls[t - off] : 0;
        __syncthreads();
        ls[t] += add;
        __syncthreads();
    }
    if (t < nb) bsum[t] = ls[t] - v;
}

__global__ __launch_bounds__(256)
void perm_kernel(const int* __restrict__ src, const int* __restrict__ rank,
                 const int* __restrict__ offs, const int* __restrict__ bsum,
                 int* __restrict__ perm) {
    int e = blockIdx.x * 256 + threadIdx.x;
    int s = src[e];
    perm[offs[s] + bsum[s >> 8] + rank[e]] = e;
}

// coalesced-write gather: ssorted (for epilogue int4), sd pairs (own-edge), ef16
__global__ __launch_bounds__(256)
void gather_kernel(const int* __restrict__ perm,
                   const int* __restrict__ src, const int* __restrict__ dst,
                   const float* __restrict__ ef,
                   int* __restrict__ ssorted, int2* __restrict__ sdsorted,
                   _Float16* __restrict__ ef16) {
    int pos = blockIdx.x * 256 + threadIdx.x;
    int e = perm[pos];
    int s = src[e], d = dst[e];
    ssorted[pos] = s;
    int2 sd; sd.x = s; sd.y = d;
    sdsorted[pos] = sd;
    const float2* efe = (const float2*)(ef + (size_t)e * F_EDGE);
    uint* op = (uint*)(ef16 + (size_t)pos * EFSTR);
#pragma unroll
    for (int i = 0; i < 5; i++) {
        float2 v = efe[i];
        _Float16 h0 = (_Float16)v.x;
        _Float16 h1 = (_Float16)v.y;
        op[i] = (uint)*(unsigned short*)&h0 | ((uint)*(unsigned short*)&h1 << 16);
    }
    op[5] = 0u;
}

// weights -> f16 transposed [layer][n][k], pre-scaled by -log2e (gate) / +log2e (cand)
__global__ __launch_bounds__(256)
void prep_w_kernel(const float* __restrict__ gw, const float* __restrict__ cw,
                   _Float16* __restrict__ wT) {
    int idx = blockIdx.x * 256 + threadIdx.x;
    if (idx >= 3 * 128 * 160) return;
    int k = idx % 160;
    int n = (idx / 160) & 127;
    int layer = idx / (160 * 128);
    float v = 0.f;
    if (k < IN_DIM)
        v = (n < 64) ? (-LOG2E) * gw[layer * IN_DIM * HH + k * HH + n]
                     : ( LOG2E) * cw[layer * IN_DIM * HH + k * HH + (n - 64)];
    wT[idx] = (_Float16)v;
}

// ---------------- embed (writes h16 only) ----------------
__global__ __launch_bounds__(256)
void embed_kernel(const float* __restrict__ nf, const float* __restrict__ w,
                  const float* __restrict__ bias, _Float16* __restrict__ h16, int n) {
    __shared__ float wl[F_NODE * HH];
    int tid = threadIdx.x;
    for (int i = tid; i < F_NODE * HH; i += 256) wl[i] = w[i];
    __syncthreads();
    int idx = blockIdx.x * 256 + tid;
    int node = idx >> 6, j = idx & 63;
    if (node >= n) return;
    float acc = bias[j];
    const float* row = nf + node * F_NODE;
#pragma unroll
    for (int k = 0; k < F_NODE; k++) acc += row[k] * wl[k * HH + j];
    h16[idx] = (_Float16)acc;
}

// ---------------- conv: barrier-free, LDS-free, col-split (R6 skeleton) ----------------
__device__ __forceinline__ void loadA(uint4* A,
                                      const _Float16* __restrict__ h16,
                                      const _Float16* __restrict__ ef16,
                                      int s, int d, int eg, int quad) {
    const uint4* hs = (const uint4*)(h16 + (size_t)s * HH);
    const uint4* hd = (const uint4*)(h16 + (size_t)d * HH);
    A[0] = hs[quad];
    A[1] = hs[quad + 4];
    A[2] = hd[quad];
    A[3] = hd[quad + 4];
    uint4 z; z.x = z.y = z.z = z.w = 0u;
    A[4] = z;
    const _Float16* p = ef16 + (size_t)eg * EFSTR;
    if (quad == 0) {
        uint2 a = *(const uint2*)p;
        uint2 b = *(const uint2*)(p + 4);
        A[4].x = a.x; A[4].y = a.y; A[4].z = b.x; A[4].w = b.y;
    } else if (quad == 1) {
        uint2 a = *(const uint2*)(p + 8);
        A[4].x = a.x; A[4].y = a.y;
    }
}

__global__ __launch_bounds__(128, 3)
void edge_conv_mfma(const _Float16* __restrict__ h16,
                    const int* __restrict__ ssorted,
                    const int2* __restrict__ sdsorted,
                    const _Float16* __restrict__ ef16,
                    const _Float16* __restrict__ wT,
                    const float* __restrict__ gb, const float* __restrict__ cb,
                    float* __restrict__ agg) {
    int lane = threadIdx.x & 63;
    int w = threadIdx.x >> 6;          // wave 0/1: col-split
    int quad = lane >> 4, n15 = lane & 15;
    int blockE = blockIdx.x * EPB;
    int base = blockE + ((n15 >> 2) * SUBLEN) + (n15 & 3);
    int ebase_epi = blockE + quad * SUBLEN;   // + g*4 + r : this lane's C rows

    // this wave's 4 B-tiles: gate {2w,2w+1}, cand {4+2w,4+2w+1} -> 80 VGPRs
    int tg = 2 * w;
    half8 B[4][5];
#pragma unroll
    for (int j = 0; j < 2; j++) {
        const _Float16* wrg = wT + ((tg + j) * 16 + n15) * 160 + quad * 8;
        const _Float16* wrc = wT + ((4 + tg + j) * 16 + n15) * 160 + quad * 8;
#pragma unroll
        for (int ks = 0; ks < 5; ks++) {
            B[j][ks]     = *(const half8*)(wrg + ks * 32);
            B[2 + j][ks] = *(const half8*)(wrc + ks * 32);
        }
    }
    // biases pre-scaled to match weight scaling
    float gb0 = -LOG2E * gb[tg * 16 + n15], gb1 = -LOG2E * gb[(tg + 1) * 16 + n15];
    float cb0 =  LOG2E * cb[tg * 16 + n15], cb1 =  LOG2E * cb[(tg + 1) * 16 + n15];
    int colbase = tg * 16 + n15;

    int sprev = -1;
    float am0 = 0.f, am1 = 0.f;

    // 1-deep pipeline (R6-proven): A holds group g; sdn holds indices for g+1
    uint4 A[5];
    {
        int2 sd0 = sdsorted[base];
        loadA(A, h16, ef16, sd0.x, sd0.y, base, quad);
    }
    int2 sdn = sdsorted[base + 4];

    for (int g = 0; g < NGROUPS; g++) {
        // epilogue srcs for this group's 4 C-rows: consecutive -> one int4
        int4 ss = *(const int4*)&ssorted[ebase_epi + g * 4];

        // accumulators init with pre-scaled bias
        floatx4 acc[4];
        acc[0] = (floatx4){gb0, gb0, gb0, gb0};
        acc[1] = (floatx4){gb1, gb1, gb1, gb1};
        acc[2] = (floatx4){cb0, cb0, cb0, cb0};
        acc[3] = (floatx4){cb1, cb1, cb1, cb1};

#pragma unroll
        for (int ks = 0; ks < 5; ks++) {
            half8 a = __builtin_bit_cast(half8, A[ks]);
#pragma unroll
            for (int t = 0; t < 4; t++)
                acc[t] = __builtin_amdgcn_mfma_f32_16x16x32_f16(a, B[t][ks], acc[t], 0, 0, 0);
        }

        // refill A for group g+1 (indices prefetched last iteration)
        int gl = (g + 1 < NGROUPS) ? g + 1 : NGROUPS - 1;
        loadA(A, h16, ef16, sdn.x, sdn.y, base + gl * 4, quad);
        int gp = (g + 2 < NGROUPS) ? g + 2 : NGROUPS - 1;
        sdn = sdsorted[base + gp * 4];

        // epilogue: batch the 8 activations (keeps trans pipe busy), then merge
        float mm0[4], mm1[4];
#pragma unroll
        for (int r = 0; r < 4; r++) {
            mm0[r] = mpair_pre(acc[0][r], acc[2][r]);
            mm1[r] = mpair_pre(acc[1][r], acc[3][r]);
        }
        int srr[4] = {ss.x, ss.y, ss.z, ss.w};
#pragma unroll
        for (int r = 0; r < 4; r++) {
            int sr = srr[r];
            if (sr != sprev) {
                if (sprev >= 0) {
                    float* p = agg + (size_t)sprev * HH + colbase;
                    atomicAdd(p, am0);
                    atomicAdd(p + 16, am1);
                }
                sprev = sr;
                am0 = am1 = 0.f;
            }
            am0 = fmaf(mm0[r], LN2, am0);
            am1 = fmaf(mm1[r], LN2, am1);
        }
    }
    if (sprev >= 0) {
        float* p = agg + (size_t)sprev * HH + colbase;
        atomicAdd(p, am0);
        atomicAdd(p + 16, am1);
    }
}

// ---------------- BN ----------------
__global__ __launch_bounds__(256)
void bn_stats_kernel(const float* __restrict__ agg, float* __restrict__ stats, int total) {
    __shared__ float ls[256], lss[256];
    int tid = threadIdx.x;
    float s = 0.f, ss = 0.f;
    for (int idx = blockIdx.x * 256 + tid; idx < total; idx += gridDim.x * 256) {
        float v = agg[idx];
        s += v;
        ss += v * v;
    }
    ls[tid] = s;
    lss[tid] = ss;
    __syncthreads();
    if (tid < 64) {
        s = ls[tid] + ls[tid + 64] + ls[tid + 128] + ls[tid + 192];
        ss = lss[tid] + lss[tid + 64] + lss[tid + 128] + lss[tid + 192];
        atomicAdd(&stats[tid], s);
        atomicAdd(&stats[64 + tid], ss);
    }
}

// h16 = softplus(h16 + BN(agg)); zeroes agg for next layer
__global__ __launch_bounds__(256)
void bn_update_kernel(_Float16* __restrict__ h16,
                      float* __restrict__ agg,
                      const float* __restrict__ stats,
                      const float* __restrict__ g, const float* __restrict__ b,
                      int total, float invN) {
    int idx = blockIdx.x * 256 + threadIdx.x;
    if (idx >= total) return;
    int j = idx & 63;
    float mu = stats[j] * invN;
    float var = stats[64 + j] * invN - mu * mu;
    var = fmaxf(var, 0.0f);
    float scale = g[j] * rsqrtf(var + EPSBN);
    float a = agg[idx];
    agg[idx] = 0.f;
    float v = (float)h16[idx] + (a - mu) * scale + b[j];
    h16[idx] = (_Float16)softplus_fast(v);
}

// ---------------- pool (reads h16) ----------------
__global__ __launch_bounds__(256)
void pool_kernel(const _Float16* __restrict__ h16, const int* __restrict__ gi,
                 float* __restrict__ pool, float* __restrict__ counts, int n) {
    int tid = threadIdx.x;
    int grp = tid >> 6;
    int j = tid & 63;
    int n0 = blockIdx.x * 64 + grp * 16;
    if (n0 >= n) return;
    int nend = n0 + 16; if (nend > n) nend = n;
    int gprev = gi[n0];
    float a = 0.f;
    int cnt = 0;
    for (int nn = n0; nn < nend; nn++) {
        int gg = gi[nn];
        if (gg != gprev) {
            atomicAdd(&pool[gprev * 64 + j], a);
            if (j == 0) atomicAdd(&counts[gprev], (float)cnt);
            a = 0.f; cnt = 0; gprev = gg;
        }
        a += (float)h16[(size_t)nn * 64 + j];
        cnt++;
    }
    atomicAdd(&pool[gprev * 64 + j], a);
    if (j == 0) atomicAdd(&counts[gprev], (float)cnt);
}

__global__ __launch_bounds__(128)
void mlp_kernel(const float* __restrict__ pool, const float* __restrict__ counts,
                const float* __restrict__ w1, const float* __restrict__ b1,
                const float* __restrict__ w2, const float* __restrict__ b2,
                const float* __restrict__ w3, const float* __restrict__ b3,
                float* __restrict__ out) {
    __shared__ float x0[64], x1[128], x2[64];
    int b = blockIdx.x, t = threadIdx.x;
    if (t < 64) {
        float c = counts[b];
        c = c < 1.f ? 1.f : c;
        x0[t] = pool[b * 64 + t] / c;
    }
    __syncthreads();
    {
        float acc = 0.f;
#pragma unroll
        for (int k = 0; k < 64; k++) acc += x0[k] * w1[k * 128 + t];
        x1[t] = softplus_fast(acc + b1[t]);
    }
    __syncthreads();
    if (t < 64) {
        float acc = 0.f;
#pragma unroll
        for (int k = 0; k < 128; k++) acc += x1[k] * w2[k * 64 + t];
        x2[t] = softplus_fast(acc + b2[t]);
    }
    __syncthreads();
    if (t == 0) {
        float acc = 0.f;
        for (int k = 0; k < 64; k++) acc += x2[k] * w3[k];
        out[b] = acc + b3[0];
    }
}

extern "C" void kernel_launch(void* const* d_in, const int* in_sizes, int n_in,
                              void* d_out, int out_size, void* d_ws, size_t ws_size,
                              hipStream_t stream) {
    const float* nf      = (const float*)d_in[0];
    const int*   ei      = (const int*)d_in[1];
    const float* ef      = (const float*)d_in[2];
    const int*   gi      = (const int*)d_in[3];
    const float* embed_w = (const float*)d_in[4];
    const float* embed_b = (const float*)d_in[5];
    const float* gate_w  = (const float*)d_in[6];
    const float* gate_b  = (const float*)d_in[7];
    const float* cand_w  = (const float*)d_in[8];
    const float* cand_b  = (const float*)d_in[9];
    const float* bn_g    = (const float*)d_in[10];
    const float* bn_b    = (const float*)d_in[11];
    const float* w1      = (const float*)d_in[12];
    const float* b1      = (const float*)d_in[13];
    const float* w2      = (const float*)d_in[14];
    const float* b2      = (const float*)d_in[15];
    const float* w3      = (const float*)d_in[16];
    const float* b3      = (const float*)d_in[17];
    float* out = (float*)d_out;

    const int NH = NN * HH;  // 6.4M
    char* p = (char*)d_ws;
    // --- zero-initialized block (single memset) ---
    int*       offs    = (int*)p;              p += (size_t)NN * 4;
    float*     agg     = (float*)p;            p += (size_t)NH * 4;
    float*     stats   = (float*)p;            p += 3 * 128 * 4;
    float*     pool    = (float*)p;            p += (size_t)BB * HH * 4;
    float*     counts  = (float*)p;            p += (size_t)BB * 4;
    size_t zero_bytes = (size_t)(p - (char*)d_ws);
    // --- rest ---
    _Float16*  h16     = (_Float16*)p;         p += (size_t)NH * 2;
    int*       ssorted = (int*)p;              p += (size_t)EE * 4;
    int2*      sdsorted= (int2*)p;             p += (size_t)EE * 8;
    _Float16*  ef16    = (_Float16*)p;         p += (size_t)EE * EFSTR * 2;
    int*       perm    = (int*)p;              p += (size_t)EE * 4;
    int*       rank    = (int*)p;              p += (size_t)EE * 4;
    _Float16*  wTall   = (_Float16*)p;         p += (size_t)3 * 128 * 160 * 2;
    int*       bsum    = (int*)p;              p += 512 * 4;

    const int* src = ei;
    const int* dst = ei + EE;

    hipMemsetAsync(d_ws, 0, zero_bytes, stream);

    // ---- sort edges by src + weight prep ----
    hist_rank_kernel<<<EE / 256, 256, 0, stream>>>(src, offs, rank);
    prep_w_kernel<<<(3 * 128 * 160 + 255) / 256, 256, 0, stream>>>(gate_w, cand_w, wTall);
    scan1_kernel<<<NB1, 256, 0, stream>>>(offs, bsum, NN);
    scan2_kernel<<<1, 512, 0, stream>>>(bsum, NB1);
    perm_kernel<<<EE / 256, 256, 0, stream>>>(src, rank, offs, bsum, perm);
    gather_kernel<<<EE / 256, 256, 0, stream>>>(perm, src, dst, ef, ssorted, sdsorted, ef16);

    // ---- embed ----
    embed_kernel<<<NH / 256, 256, 0, stream>>>(nf, embed_w, embed_b, h16, NN);

    // ---- conv layers ----
    for (int i = 0; i < N_CONV; i++) {
        edge_conv_mfma<<<NBLK, 128, 0, stream>>>(
            h16, ssorted, sdsorted, ef16,
            wTall + (size_t)i * 128 * 160,
            gate_b + i * HH, cand_b + i * HH, agg);
        bn_stats_kernel<<<512, 256, 0, stream>>>(agg, stats + i * 128, NH);
        bn_update_kernel<<<NH / 256, 256, 0, stream>>>(
            h16, agg, stats + i * 128, bn_g + i * HH, bn_b + i * HH, NH, 1.0f / (float)NN);
    }

    // ---- pool + MLP ----
    pool_kernel<<<(NN + 63) / 64, 256, 0, stream>>>(h16, gi, pool, counts, NN);
    mlp_kernel<<<BB, 128, 0, stream>>>(pool, counts, w1, b1, w2, b2, w3, b3, out);
}